// Round 9
// baseline (86.892 us; speedup 1.0000x reference)
//
#include <hip/hip_runtime.h>
#include <stdint.h>

// SSIM fused kernel v9, MI355X (gfx950).
// v8 post-mortem: WIN (118->93 us rocprof), but SQ_LDS_BANK_CONFLICT 0->1.6e7.
// Diagnosis: rbAB row stride 128 words = 0 mod 32 (all rows same bank phase;
// stage-1 uint4 writes hit 16 of 32 banks at 2x density) and sp/st stride 80
// = 16 mod 32 (only 2 row phases). v9 = v8 + padding only:
//  - rbAB [26][64] -> [26][66]: stride 132 words = 4 mod 32 -> row phases
//    0/4/8/12 across a wave's 4 rows -> uniform write distribution.
//  - sp/st row stride 80 -> 84 floats (= 20 mod 32, 8 row phases, 16B
//    alignment kept). Staged region stays 80 cols; cols 80..83 unused.
// Everything else identical to v8 (f32 accum, pk-f32 conv math, RTN fp16
// storage of row-conv results, 2-kernel deterministic mean).

#define HH 512
#define WW 512
#define PLANES 48
#define TW 64
#define TH 16
#define RR 5
#define KK 11
#define IN_H (TH + 2 * RR)        // 26
#define SW 84                      // sp/st row stride (staged cols: 80 used)
#define RBP 66                     // rbAB padded row stride (uint2)
#define NBLOCKS (PLANES * (WW / TW) * (HH / TH))  // 12288
#define NTHREADS 256
#define NITEMS (IN_H * (TW / 4))  // 416
#define NSTAGE (IN_H * 20)        // 520 staging granules (80 cols / 4)
#define TOTAL_ELEMS (PLANES * HH * WW)

typedef _Float16 half2v __attribute__((ext_vector_type(2)));
typedef float float2v __attribute__((ext_vector_type(2)));

constexpr float G_[KK] = {
    1.4867195147342977e-06f, 1.3383022576488537e-04f, 4.4318484119380075e-03f,
    5.3990966513188063e-02f, 2.4197072451914337e-01f, 3.9894228040143270e-01f,
    2.4197072451914337e-01f, 5.3990966513188063e-02f, 4.4318484119380075e-03f,
    1.3383022576488537e-04f, 1.4867195147342977e-06f};

__device__ __forceinline__ half2v u2h(uint32_t u) {
  return __builtin_bit_cast(half2v, u);
}
// RTN fp16 pack — unbiased (v4/v8 verified; RTZ pack is NOT safe, v7).
__device__ __forceinline__ uint32_t packrtn(float a, float b) {
  half2v h = {(_Float16)a, (_Float16)b};
  return __builtin_bit_cast(uint32_t, h);
}

__global__ __launch_bounds__(NTHREADS, 4) void ssim_tile_kernel(
    const float* __restrict__ pred, const float* __restrict__ targ,
    float* __restrict__ partial) {
  __shared__ __align__(16) float sp[IN_H][SW];    // 8.7 KB raw pred
  __shared__ __align__(16) float st[IN_H][SW];    // 8.7 KB raw targ
  __shared__ __align__(16) uint2 rbAB[IN_H][RBP]; // 13.7 KB {pack(p,t),pack(pp,tt)}
  __shared__ __align__(16) float rbC[IN_H][TW];   // 6.7 KB conv_pt f32
  __shared__ float wsums[4];

  const int tid = threadIdx.x;
  const int bid = blockIdx.x;
  const int plane = bid >> 8;
  const int tile = bid & 255;
  const int x0 = (tile & 7) * TW;
  const int y0 = (tile >> 3) * TH;
  const float* pp = pred + (size_t)plane * (HH * WW);
  const float* tp = targ + (size_t)plane * (HH * WW);

  // ---- Stage 0: stage raw halo (granule-aligned float4, uniform path) ----
  for (int i = tid; i < NSTAGE; i += NTHREADS) {
    const int r = i / 20;            // halo row 0..25
    const int cg = i - r * 20;       // granule 0..19
    const int gy = y0 + r - RR;
    const int gx = x0 - 8 + cg * 4;  // granule start, 16B aligned
    float4 pv = make_float4(0.f, 0.f, 0.f, 0.f);
    float4 tv = pv;
    if (gy >= 0 && gy < HH && gx >= 0 && gx <= WW - 4) {
      const int o = gy * WW + gx;
      pv = *reinterpret_cast<const float4*>(pp + o);
      tv = *reinterpret_cast<const float4*>(tp + o);
    }
    *reinterpret_cast<float4*>(&sp[r][cg * 4]) = pv;
    *reinterpret_cast<float4*>(&st[r][cg * 4]) = tv;
  }
  __syncthreads();

  // ---- Stage 1: row conv of 5 quantities, packed f32 math ----
  for (int i = tid; i < NITEMS; i += NTHREADS) {
    const int r = i >> 4;            // 0..25
    const int c4 = (i & 15) << 2;    // 0..60
    // staged window cols c4 .. c4+19 (global x0+c4-8 .. x0+c4+11)
    float pw[20], tw[20];
#pragma unroll
    for (int u = 0; u < 5; ++u) {
      float4 a = *reinterpret_cast<const float4*>(&sp[r][c4 + 4 * u]);
      float4 b = *reinterpret_cast<const float4*>(&st[r][c4 + 4 * u]);
      pw[4*u+0] = a.x; pw[4*u+1] = a.y; pw[4*u+2] = a.z; pw[4*u+3] = a.w;
      tw[4*u+0] = b.x; tw[4*u+1] = b.y; tw[4*u+2] = b.z; tw[4*u+3] = b.w;
    }

    float2v s01[4] = {{0,0},{0,0},{0,0},{0,0}};
    float2v s23[4] = {{0,0},{0,0},{0,0},{0,0}};
    float s4[4] = {0,0,0,0};
#pragma unroll
    for (int idx = 3; idx <= 16; ++idx) {
      const float a = pw[idx];
      const float b = tw[idx];
      const float2v av = {a, b};
      const float2v sq = av * av;      // v_pk_mul_f32
      const float ab = a * b;
#pragma unroll
      for (int j = 0; j < 4; ++j) {
        if (j < idx - 13 || j > idx - 3) continue;
        const float w = G_[idx - 3 - j];
        const float2v w2 = {w, w};
        s01[j] = __builtin_elementwise_fma(w2, av, s01[j]);  // v_pk_fma_f32
        s23[j] = __builtin_elementwise_fma(w2, sq, s23[j]);
        s4[j] = fmaf(w, ab, s4[j]);
      }
    }

    uint4 w1, w2s;
    w1.x = packrtn(s01[0].x, s01[0].y); w1.y = packrtn(s23[0].x, s23[0].y);
    w1.z = packrtn(s01[1].x, s01[1].y); w1.w = packrtn(s23[1].x, s23[1].y);
    w2s.x = packrtn(s01[2].x, s01[2].y); w2s.y = packrtn(s23[2].x, s23[2].y);
    w2s.z = packrtn(s01[3].x, s01[3].y); w2s.w = packrtn(s23[3].x, s23[3].y);
    *reinterpret_cast<uint4*>(&rbAB[r][c4]) = w1;
    *reinterpret_cast<uint4*>(&rbAB[r][c4 + 2]) = w2s;
    *reinterpret_cast<float4*>(&rbC[r][c4]) =
        make_float4(s4[0], s4[1], s4[2], s4[3]);
  }
  __syncthreads();

  // ---- Stage 2: column conv (packed f32) + SSIM map ----
  float lsum = 0.f;
  {
    const int x = tid & 63;
    const int ybase = (tid >> 6) * 4;  // 0,4,8,12
    // read packed rows once, unpack to f32 pairs
    float2v fa[14], fb[14];
    float vc[14];
#pragma unroll
    for (int m = 0; m < 14; ++m) {
      uint2 q = rbAB[ybase + m][x];    // ds_read_b64
      half2v ha = u2h(q.x), hb = u2h(q.y);
      fa[m] = float2v{(float)ha.x, (float)ha.y};
      fb[m] = float2v{(float)hb.x, (float)hb.y};
      vc[m] = rbC[ybase + m][x];
    }

    float2v accA[4], accB[4];
    float sC[4];
#pragma unroll
    for (int j = 0; j < 4; ++j) {
      float2v a = {0, 0}, b = {0, 0};
      float c = 0.f;
#pragma unroll
      for (int k = 0; k < KK; ++k) {
        const float2v w2 = {G_[k], G_[k]};
        a = __builtin_elementwise_fma(w2, fa[j + k], a);
        b = __builtin_elementwise_fma(w2, fb[j + k], b);
        c = fmaf(G_[k], vc[j + k], c);
      }
      accA[j] = a; accB[j] = b; sC[j] = c;
    }

    const float C1 = 1.0e-4f;
    const float C2 = 9.0e-4f;
#pragma unroll
    for (int j = 0; j < 4; ++j) {
      float mu_x = accA[j].x;
      float mu_y = accA[j].y;
      float sxx = accB[j].x - mu_x * mu_x;
      float syy = accB[j].y - mu_y * mu_y;
      float sxy = sC[j] - mu_x * mu_y;
      float num = (2.f * mu_x * mu_y + C1) * (2.f * sxy + C2);
      float den = (mu_x * mu_x + mu_y * mu_y + C1) *
                  (sxx * sxx + syy * syy + C2);
      lsum = fmaf(num, __builtin_amdgcn_rcpf(den), lsum);
    }
  }

  // ---- Block reduction -> partial[bid] ----
#pragma unroll
  for (int off = 32; off > 0; off >>= 1) lsum += __shfl_xor(lsum, off, 64);
  if ((tid & 63) == 0) wsums[tid >> 6] = lsum;
  __syncthreads();
  if (tid == 0)
    partial[bid] = (wsums[0] + wsums[1]) + (wsums[2] + wsums[3]);
}

__global__ __launch_bounds__(1024) void ssim_reduce_kernel(
    const float* __restrict__ partial, float* __restrict__ out) {
  float s = 0.f;
  for (int i = threadIdx.x; i < NBLOCKS; i += 1024) s += partial[i];
#pragma unroll
  for (int off = 32; off > 0; off >>= 1) s += __shfl_xor(s, off, 64);
  __shared__ float ws[16];
  if ((threadIdx.x & 63) == 0) ws[threadIdx.x >> 6] = s;
  __syncthreads();
  if (threadIdx.x == 0) {
    float t = 0.f;
#pragma unroll
    for (int i = 0; i < 16; ++i) t += ws[i];
    out[0] = t * (1.0f / (float)TOTAL_ELEMS);
  }
}

extern "C" void kernel_launch(void* const* d_in, const int* in_sizes, int n_in,
                              void* d_out, int out_size, void* d_ws,
                              size_t ws_size, hipStream_t stream) {
  const float* pred = (const float*)d_in[0];
  const float* targ = (const float*)d_in[1];
  float* out = (float*)d_out;
  float* partial = (float*)d_ws;

  ssim_tile_kernel<<<NBLOCKS, NTHREADS, 0, stream>>>(pred, targ, partial);
  ssim_reduce_kernel<<<1, 1024, 0, stream>>>(partial, out);
}